// Round 10
// baseline (141.647 us; speedup 1.0000x reference)
//
#include <hip/hip_runtime.h>
#include <hip/hip_bf16.h>

#define D 256
#define TEMP_INV 20.0f        // 1 / 0.05
#define K_EXP2 28.85390081777927f   // 20 / ln(2): e^(20x) = 2^(K_EXP2*x)
#define NJ 16                 // 128-col tiles per colgroup (2048 cols per block)
#define NS (NJ * 4)           // K-steps per block (BK=64, K=256 -> 4 per j-tile)

typedef __attribute__((ext_vector_type(8))) short bf16x8s;  // 8 bf16 in 4 VGPRs
typedef __attribute__((ext_vector_type(4))) float f32x4;

// ---- helpers ----------------------------------------------------------------
__device__ __forceinline__ unsigned short f2bf(float f) {
  unsigned u = __float_as_uint(f);
  unsigned r = u + 0x7FFFu + ((u >> 16) & 1u);
  return (unsigned short)(r >> 16);
}

__device__ __forceinline__ void gld16(const void* g, void* l) {
  // async global->LDS, 16B/lane; LDS dest is wave-uniform base + lane*16
  __builtin_amdgcn_global_load_lds(
      (const __attribute__((address_space(1))) void*)g,
      (__attribute__((address_space(3))) void*)l, 16, 0, 0);
}

// ---- kernel 1: fused row L2-normalize f32 -> bf16 (3 inputs) + zero rowsum --
__global__ __launch_bounds__(256) void nce_normalize(const float* __restrict__ anc,
                                                     const float* __restrict__ pos,
                                                     const float* __restrict__ neg,
                                                     unsigned short* __restrict__ An,
                                                     unsigned short* __restrict__ Tn,
                                                     float* __restrict__ rowsum,
                                                     int B) {
  int zi = blockIdx.x * 256 + threadIdx.x;
  if (blockIdx.x < (B + 255) / 256 && zi < B) rowsum[zi] = 0.0f;

  const int lane = threadIdx.x & 63;
  const int wid  = threadIdx.x >> 6;
  const int sub  = lane >> 4, lr = lane & 15;
  int row = blockIdx.x * 16 + wid * 4 + sub;

  const float* src;
  unsigned short* dst;
  int r2;
  if (row < B)          { src = anc; dst = An; r2 = row; }
  else if (row < 2 * B) { src = pos; dst = Tn; r2 = row - B; }
  else                  { src = neg; dst = Tn + (size_t)B * D; r2 = row - 2 * B; }

  const float4* sp = reinterpret_cast<const float4*>(src) + (size_t)r2 * (D / 4);
  float4 v[4];
#pragma unroll
  for (int c = 0; c < 4; ++c) v[c] = sp[lr + c * 16];
  float ss = 0.0f;
#pragma unroll
  for (int c = 0; c < 4; ++c)
    ss += v[c].x * v[c].x + v[c].y * v[c].y + v[c].z * v[c].z + v[c].w * v[c].w;
  ss += __shfl_xor(ss, 1, 64);
  ss += __shfl_xor(ss, 2, 64);
  ss += __shfl_xor(ss, 4, 64);
  ss += __shfl_xor(ss, 8, 64);
  float inv = rsqrtf(fmaxf(ss, 1e-24f));
  ushort4* dp = reinterpret_cast<ushort4*>(dst) + (size_t)r2 * (D / 4);
#pragma unroll
  for (int c = 0; c < 4; ++c) {
    ushort4 o;
    o.x = f2bf(v[c].x * inv);
    o.y = f2bf(v[c].y * inv);
    o.z = f2bf(v[c].z * inv);
    o.w = f2bf(v[c].w * inv);
    dp[lr + c * 16] = o;
  }
}

// ---- kernel 2: A-in-registers MFMA GEMM, BK=64, half-split + block stagger --
// R8 base (proven: 0 conflicts, absmax 0), two additive changes:
//  * anti-phase stagger: each block sleeps 0..960 cyc (pseudo-random in
//    blockIdx) after issuing its prefetch DMAs, so the two co-resident
//    blocks per CU stop phase-locking their MFMA bursts on the shared
//    matrix pipe (m114 overlap needs anti-phase).
//  * half-split step: read h0 frags, STAGE, read h1 frags, lgkmcnt(4)
//    (h0 ready, h1 in flight), MFMA h0 x16, lgkmcnt(0), MFMA h1 x16 —
//    h1's LDS latency hides under h0's MFMA burst.
// Buffer safety unchanged: one barrier/step; reads of buf(s) all retire at
// this step's lgkmcnt(0) (before next barrier); STAGE(s+3) overwrites
// buf(s-1) whose readers drained at step s-1's lgkmcnt(0). vmcnt(8) at step
// top proves stage(s) landed (outstanding then: stages s+1,s+2 = 8 loads).
__global__ __launch_bounds__(256, 2) void nce_scores(const unsigned short* __restrict__ A,
                                                     const unsigned short* __restrict__ T,
                                                     float* __restrict__ rowsum,
                                                     float* __restrict__ diag) {
  __shared__ unsigned char smem[4][16384];   // B tile ring (BK=64)

  const int tid  = threadIdx.x;
  const int lane = tid & 63;
  const int wid  = __builtin_amdgcn_readfirstlane(tid >> 6);
  const int wr = wid >> 1, wc = wid & 1;
  const int row0 = blockIdx.y * 128;
  const int cg   = blockIdx.x;              // colgroup: cols [cg*2048, +2048)
  const int r = lane & 15, g = lane >> 4;

  // ---- staging source address (inverse swizzle) ----
  const int Rl = lane >> 3;                 // row within 8-row group
  const int Cl = (lane & 7) ^ Rl;           // source chunk
  const unsigned char* gB = (const unsigned char*)T +
      (((size_t)(cg * 2048 + wid * 32 + Rl)) << 9) + Cl * 16;

  auto STAGE = [&](int s) {                 // dst buffer = s & 3
    const unsigned char* gb = gB + (size_t)(s >> 2) * 65536 + (s & 3) * 128;
    unsigned char* sb = &smem[s & 3][0];
#pragma unroll
    for (int q = 0; q < 4; ++q)             // rows [wid*32+q*8, +8)
      gld16(gb + q * 4096, sb + wid * 4096 + q * 1024);
  };

  // ---- fragment read offsets (swizzled), within one 16KB buffer ----
  // frag (ks,n): row R = wc*64 + n*16 + r; chunk (ks*4+g)^(r&7)
  const int rx = r & 7;
  int offB[2][4];
#pragma unroll
  for (int ks = 0; ks < 2; ++ks)
#pragma unroll
    for (int n = 0; n < 4; ++n)
      offB[ks][n] = wc * 8192 + n * 2048 + r * 128 + ((((ks << 2) | g) ^ rx) << 4);

  // ---- load the wave's whole A panel into registers (64 rows x 256 K) ----
  const unsigned short* aPtr = A + (size_t)(row0 + wr * 64 + r) * D + g * 8;
  bf16x8s aF[4][8];
#pragma unroll
  for (int m = 0; m < 4; ++m)
#pragma unroll
    for (int t = 0; t < 8; ++t)
      aF[m][t] = *reinterpret_cast<const bf16x8s*>(aPtr + (size_t)m * 16 * D + t * 32);
  __builtin_amdgcn_sched_barrier(0);        // keep aF issues before STAGE issues

  // prefetch depth 3 (12 gload_lds in flight)
  STAGE(0);
  STAGE(1);
  STAGE(2);

  // ---- anti-phase stagger: 0..15 x ~64 cyc, block-uniform, DMA in flight ----
  {
    const int st = (blockIdx.y * 7 + blockIdx.x * 3) & 15;
    for (int i = 0; i < st; ++i) asm volatile("s_sleep 1" ::: "memory");
  }

  float rs[4][4];
#pragma unroll
  for (int m = 0; m < 4; ++m)
#pragma unroll
    for (int reg = 0; reg < 4; ++reg) rs[m][reg] = 0.0f;

  for (int j = 0; j < NJ; ++j) {
    f32x4 acc[4][4];
#pragma unroll
    for (int m = 0; m < 4; ++m)
#pragma unroll
      for (int n = 0; n < 4; ++n) acc[m][n] = (f32x4)0.0f;

#pragma unroll
    for (int kt = 0; kt < 4; ++kt) {
      const int s = j * 4 + kt;             // s & 3 == kt (compile-time buf idx)
      asm volatile("s_waitcnt vmcnt(8)" ::: "memory");
      __builtin_amdgcn_s_barrier();
      const unsigned char* sb = &smem[kt][0];
      bf16x8s bF[2][4];
      // h0 reads
#pragma unroll
      for (int n = 0; n < 4; ++n)
        bF[0][n] = *reinterpret_cast<const bf16x8s*>(sb + offB[0][n]);
      if (s + 3 < NS) STAGE(s + 3);
      // h1 reads
#pragma unroll
      for (int n = 0; n < 4; ++n)
        bF[1][n] = *reinterpret_cast<const bf16x8s*>(sb + offB[1][n]);
      asm volatile("s_waitcnt lgkmcnt(4)" ::: "memory");   // h0 ready
      __builtin_amdgcn_sched_barrier(0);
      __builtin_amdgcn_s_setprio(1);
#pragma unroll
      for (int m = 0; m < 4; ++m)
#pragma unroll
        for (int n = 0; n < 4; ++n)
          acc[m][n] = __builtin_amdgcn_mfma_f32_16x16x32_bf16(
              aF[m][kt * 2], bF[0][n], acc[m][n], 0, 0, 0);
      __builtin_amdgcn_s_setprio(0);
      asm volatile("s_waitcnt lgkmcnt(0)" ::: "memory");   // h1 ready
      __builtin_amdgcn_sched_barrier(0);
      __builtin_amdgcn_s_setprio(1);
#pragma unroll
      for (int m = 0; m < 4; ++m)
#pragma unroll
        for (int n = 0; n < 4; ++n)
          acc[m][n] = __builtin_amdgcn_mfma_f32_16x16x32_bf16(
              aF[m][kt * 2 + 1], bF[1][n], acc[m][n], 0, 0, 0);
      __builtin_amdgcn_s_setprio(0);
      __builtin_amdgcn_sched_barrier(0);
    }

    // ---- per-tile epilogue: VALU only (exp partials in regs) ----
    // C/D layout: col = lane&15 (=r), row = g*4 + reg  [measured m89]
    const bool diagTile = (cg * NJ + j == (int)blockIdx.y);
#pragma unroll
    for (int m = 0; m < 4; ++m) {
#pragma unroll
      for (int reg = 0; reg < 4; ++reg) {
        float s = 0.0f;
#pragma unroll
        for (int n = 0; n < 4; ++n)
          s += __builtin_amdgcn_exp2f(acc[m][n][reg] * K_EXP2);   // e^(20*score)
        rs[m][reg] += s;
        // diagonal raw score: row==col when wr==wc, n==m, r==g*4+reg
        if (diagTile && wr == wc && r == g * 4 + reg)
          diag[row0 + wr * 64 + m * 16 + r] = acc[m][m][reg];
      }
    }
  }

  // ---- once per block: reduce 16-lane groups, atomic into global rowsum ----
#pragma unroll
  for (int m = 0; m < 4; ++m) {
#pragma unroll
    for (int reg = 0; reg < 4; ++reg) {
      float s = rs[m][reg];
      s += __shfl_xor(s, 1, 64);
      s += __shfl_xor(s, 2, 64);
      s += __shfl_xor(s, 4, 64);
      s += __shfl_xor(s, 8, 64);
      if (r == 0) atomicAdd(&rowsum[row0 + wr * 64 + m * 16 + g * 4 + reg], s);
    }
  }
}

// ---- kernel 3: loss_i = log(rowsum_i) - diag_i*20; mean -> scalar -----------
__global__ __launch_bounds__(1024) void nce_finalize(const float* __restrict__ rowsum,
                                                     const float* __restrict__ diag,
                                                     float* __restrict__ out, int n) {
  __shared__ float red[16];
  float s = 0.0f;
  for (int i = threadIdx.x; i < n; i += 1024)
    s += logf(rowsum[i]) - diag[i] * TEMP_INV;
#pragma unroll
  for (int m = 1; m < 64; m <<= 1) s += __shfl_xor(s, m, 64);
  if ((threadIdx.x & 63) == 0) red[threadIdx.x >> 6] = s;
  __syncthreads();
  if (threadIdx.x == 0) {
    float t = 0.0f;
#pragma unroll
    for (int i = 0; i < 16; ++i) t += red[i];
    out[0] = t / (float)n;
  }
}

// ---- launch -----------------------------------------------------------------
extern "C" void kernel_launch(void* const* d_in, const int* in_sizes, int n_in,
                              void* d_out, int out_size, void* d_ws, size_t ws_size,
                              hipStream_t stream) {
  const float* anc = (const float*)d_in[0];
  const float* pos = (const float*)d_in[1];
  const float* neg = (const float*)d_in[2];
  const int B  = in_sizes[0] / D;   // 8192
  const int N2 = 2 * B;             // 16384

  char* ws = (char*)d_ws;
  unsigned short* An = (unsigned short*)ws;                          // B*D bf16
  unsigned short* Tn = (unsigned short*)(ws + (size_t)B * D * 2);    // 2B*D bf16
  float* rowsum = (float*)(ws + (size_t)B * D * 2 + (size_t)N2 * D * 2);
  float* diag   = rowsum + B;

  nce_normalize<<<3 * B / 16, 256, 0, stream>>>(anc, pos, neg, An, Tn, rowsum, B);

  dim3 grid(N2 / (NJ * 128), B / 128);   // (8, 64) = 512 blocks = 2/CU
  nce_scores<<<grid, 256, 0, stream>>>(An, Tn, rowsum, diag);

  nce_finalize<<<1, 1024, 0, stream>>>(rowsum, diag, (float*)d_out, B);
}